// Round 17
// baseline (119.590 us; speedup 1.0000x reference)
//
#include <hip/hip_runtime.h>
#include <hip/hip_bf16.h>

#define NEG_SLOPE 0.01f
#define NPB 512          // nodes per coarse bucket (dst >> 9)
#define CHUNK 2048       // edges per block in partition pass
#define GROWS 64         // rows per GEMM block (16 per wave, 1 row-group)

typedef __attribute__((ext_vector_type(8))) short short8;
typedef __attribute__((ext_vector_type(4))) float f32x4;

__device__ __forceinline__ unsigned short f2bf_rne(float f) {
    unsigned u = __float_as_uint(f);
    u += 0x7FFFu + ((u >> 16) & 1u);       // round-to-nearest-even
    return (unsigned short)(u >> 16);
}

__device__ __forceinline__ short8 cvt2(float4 v0, float4 v1) {
    short8 o;
    o[0]=f2bf_rne(v0.x); o[1]=f2bf_rne(v0.y); o[2]=f2bf_rne(v0.z); o[3]=f2bf_rne(v0.w);
    o[4]=f2bf_rne(v1.x); o[5]=f2bf_rne(v1.y); o[6]=f2bf_rne(v1.z); o[7]=f2bf_rne(v1.w);
    return o;
}

// Fused K1: blocks [0, G1) = MFMA GEMM with B IN REGISTERS (no LDS staging,
// no barriers — each wave owns 16 rows and all of W1 as register fragments);
// blocks [G1, G1+G2) = edge partition pass.
__global__ __launch_bounds__(256, 3) void k_gp(
    const float* __restrict__ h, const float* __restrict__ W1,
    const float* __restrict__ Wa, unsigned short* __restrict__ zb,
    float* __restrict__ s, float* __restrict__ t, int N, int G1,
    const int* __restrict__ src, const int* __restrict__ dst,
    unsigned* __restrict__ gcur, unsigned* __restrict__ table,
    int E, int NBKT, int BCAP)
{
    __shared__ __align__(16) union SM {
        short tbuf[4][16 * 64];                                          // 8 KB
        struct {
            unsigned cnt[256]; unsigned exc[256]; unsigned sbuf[256];
            unsigned gbaseb[256]; unsigned stage[CHUNK];
            unsigned short bkt[CHUNK];
        } p;                                                             // 16 KB
    } sm;
    const int tid = threadIdx.x;

    if (blockIdx.x < (unsigned)G1) {
        // ---------------- GEMM path (barrier-free) ----------------
        const int w  = tid >> 6;
        const int l  = tid & 63;
        const int lr = l & 15;
        const int lc = l >> 4;
        const int rowbase = blockIdx.x * GROWS + w * 16;
        const int myn = rowbase + lr;
        const float4* __restrict__ h4 = (const float4*)h;
        const float4* __restrict__ W14 = (const float4*)W1;

        // A loads: 8 x 16B, all independent.
        float4 av[8];
#pragma unroll
        for (int ks = 0; ks < 4; ++ks) {
            const int kcb = ks * 4 + lc;
            if (myn < N) {
                av[2 * ks]     = h4[(size_t)myn * 32 + kcb * 2];
                av[2 * ks + 1] = h4[(size_t)myn * 32 + kcb * 2 + 1];
            } else {
                av[2 * ks]     = make_float4(0.f, 0.f, 0.f, 0.f);
                av[2 * ks + 1] = make_float4(0.f, 0.f, 0.f, 0.f);
            }
        }

        // B loads -> register fragments: rows {lr,16+lr,32+lr,48+lr} x 4 chunks.
        short8 bf[16];
#pragma unroll
        for (int ni = 0; ni < 4; ++ni)
#pragma unroll
            for (int ks = 0; ks < 4; ++ks) {
                const size_t base = (size_t)(ni * 16 + lr) * 32 + (ks * 4 + lc) * 2;
                bf[ni * 4 + ks] = cvt2(W14[base], W14[base + 1]);
            }

        // Convert A.
        short8 afr[4];
#pragma unroll
        for (int ks = 0; ks < 4; ++ks) afr[ks] = cvt2(av[2 * ks], av[2 * ks + 1]);

        // MFMA: acc[ni] = sum_ks A(ks) x B(ni,ks).
        f32x4 acc[4];
#pragma unroll
        for (int ni = 0; ni < 4; ++ni) acc[ni] = (f32x4){0.f, 0.f, 0.f, 0.f};
#pragma unroll
        for (int ks = 0; ks < 4; ++ks)
#pragma unroll
            for (int ni = 0; ni < 4; ++ni)
                acc[ni] = __builtin_amdgcn_mfma_f32_16x16x32_bf16(afr[ks], bf[ni * 4 + ks], acc[ni], 0, 0, 0);

        // s,t epilogue (f32 acc). C/D: col = lr, row = lc*4 + r.
        {
            float asrc[4], adst[4];
#pragma unroll
            for (int ni = 0; ni < 4; ++ni) {
                asrc[ni] = Wa[ni * 16 + lr];
                adst[ni] = Wa[64 + ni * 16 + lr];
            }
#pragma unroll
            for (int r = 0; r < 4; ++r) {
                float ps = 0.f, pt = 0.f;
#pragma unroll
                for (int ni = 0; ni < 4; ++ni) {
                    ps = fmaf(acc[ni][r], asrc[ni], ps);
                    pt = fmaf(acc[ni][r], adst[ni], pt);
                }
#pragma unroll
                for (int m = 1; m < 16; m <<= 1) {
                    ps += __shfl_xor(ps, m);
                    pt += __shfl_xor(pt, m);
                }
                const int node = rowbase + lc * 4 + r;
                if (lr == 0 && node < N) { s[node] = ps; t[node] = pt; }
            }
        }

        // z transpose via per-wave LDS (same-wave deps -> no barrier) -> 16B stores.
        {
            short* __restrict__ tb = sm.tbuf[w];
#pragma unroll
            for (int ni = 0; ni < 4; ++ni) {
                const int col = ni * 16 + lr;
#pragma unroll
                for (int r = 0; r < 4; ++r) {
                    const int ro = lc * 4 + r;
                    tb[ro * 64 + (((col >> 3) ^ (ro & 7)) << 3) + (col & 7)]
                        = (short)f2bf_rne(acc[ni][r]);
                }
            }
            const int ro = l >> 2;
            const int n = rowbase + ro;
            if (n < N) {
#pragma unroll
                for (int j = 0; j < 2; ++j) {
                    const int c = (l & 3) * 2 + j;
                    const short8 v = *(const short8*)&tb[ro * 64 + ((c ^ (ro & 7)) << 3)];
                    *(short8*)&zb[(size_t)n * 64 + c * 8] = v;
                }
            }
        }
    } else {
        // ---------------- Partition path ----------------
        const int e0 = (blockIdx.x - G1) * CHUNK;
        const int nE = min(CHUNK, E - e0);

        sm.p.cnt[tid] = 0u;
        __syncthreads();
        for (int i = tid; i < nE; i += 256)
            atomicAdd(&sm.p.cnt[(unsigned)dst[e0 + i] >> 9], 1u);
        __syncthreads();

        const unsigned myc = sm.p.cnt[tid];
        if (tid < NBKT && myc > 0u) sm.p.gbaseb[tid] = atomicAdd(&gcur[tid], myc);

        sm.p.sbuf[tid] = myc;
        __syncthreads();
        for (int off = 1; off < 256; off <<= 1) {
            unsigned x = (tid >= off) ? sm.p.sbuf[tid - off] : 0u;
            __syncthreads();
            sm.p.sbuf[tid] += x;
            __syncthreads();
        }
        sm.p.exc[tid] = sm.p.sbuf[tid] - myc;
        __syncthreads();
        sm.p.cnt[tid] = 0u;
        __syncthreads();

        for (int i = tid; i < nE; i += 256) {
            const unsigned d = (unsigned)dst[e0 + i];
            const unsigned b = d >> 9;
            const unsigned pos = sm.p.exc[b] + atomicAdd(&sm.p.cnt[b], 1u);
            sm.p.stage[pos] = ((unsigned)src[e0 + i] << 9) | (d & 511u);
            sm.p.bkt[pos] = (unsigned short)b;
        }
        __syncthreads();

        for (int i = tid; i < nE; i += 256) {
            const unsigned b = sm.p.bkt[i];
            const unsigned off = sm.p.gbaseb[b] + ((unsigned)i - sm.p.exc[b]);
            if (off < (unsigned)BCAP)
                table[(size_t)b * BCAP + off] = sm.p.stage[i];
        }
    }
}

// Pass B (one block of 512 per coarse bucket): recompute global prefix,
// LDS histogram+scan over 512 nodes, then scatter WITH per-edge softmax
// numerator p = exp(leaky(s[src]+t[dst])) and LDS-atomic denominator.
__global__ __launch_bounds__(512) void k_sp(
    const unsigned* __restrict__ table, const unsigned* __restrict__ gcur,
    const float* __restrict__ s, const float* __restrict__ t,
    uint2* __restrict__ edge_ps, unsigned* __restrict__ offsets,
    unsigned* __restrict__ counts, float* __restrict__ invden,
    int N, int NBKT, int BCAP)
{
    __shared__ unsigned ncnt[NPB], nexc[NPB], scur[NPB], sbuf[NPB];
    __shared__ float tlds[NPB], den[NPB];
    __shared__ unsigned basesh;
    const int tid = threadIdx.x;
    const int b = blockIdx.x;
    const int bc = min((int)gcur[b], BCAP);
    const size_t tbo = (size_t)b * BCAP;
    const int node = b * NPB + tid;

    {
        unsigned c = (tid < NBKT) ? min(gcur[tid], (unsigned)BCAP) : 0u;
        sbuf[tid] = c;
        __syncthreads();
        for (int off = 1; off < NPB; off <<= 1) {
            unsigned x = (tid >= off) ? sbuf[tid - off] : 0u;
            __syncthreads();
            sbuf[tid] += x;
            __syncthreads();
        }
        if (tid == 0) basesh = (b == 0) ? 0u : sbuf[b - 1];
    }
    tlds[tid] = (node < N) ? t[node] : 0.f;
    den[tid] = 0.f;
    ncnt[tid] = 0u;
    __syncthreads();
    const unsigned base = basesh;

    for (int i = tid; i < bc; i += NPB)
        atomicAdd(&ncnt[table[tbo + i] & 511u], 1u);
    __syncthreads();

    const unsigned c0 = ncnt[tid];
    sbuf[tid] = c0;
    __syncthreads();
    for (int off = 1; off < NPB; off <<= 1) {
        unsigned x = (tid >= off) ? sbuf[tid - off] : 0u;
        __syncthreads();
        sbuf[tid] += x;
        __syncthreads();
    }
    nexc[tid] = sbuf[tid] - c0;
    scur[tid] = 0u;
    __syncthreads();

    if (node < N) { offsets[node] = base + nexc[tid]; counts[node] = c0; }

    for (int i = tid; i < bc; i += NPB) {
        const unsigned v = table[tbo + i];
        const unsigned l = v & 511u;
        const unsigned sj = v >> 9;
        float e = s[sj] + tlds[l];
        e = (e >= 0.f) ? e : NEG_SLOPE * e;
        const float p = __expf(e);
        const unsigned pos = nexc[l] + atomicAdd(&scur[l], 1u);
        edge_ps[base + pos] = make_uint2(__float_as_uint(p), sj);
        atomicAdd(&den[l], p);
    }
    __syncthreads();
    if (node < N) invden[node] = 1.f / fmaxf(den[tid], 1e-16f);
}

// Pure gather-accumulate: out[node] = invden * sum p_j * z[src_j].
__global__ __launch_bounds__(256) void k_node(
    const unsigned* __restrict__ offsets, const unsigned* __restrict__ counts,
    const uint2* __restrict__ edge_ps, const float* __restrict__ invden,
    const unsigned short* __restrict__ zb, float* __restrict__ out, int N)
{
    const int tid = threadIdx.x;
    const int node = blockIdx.x * 16 + (tid >> 4);
    if (node >= N) return;
    const int wl    = tid & 63;
    const int gbase = wl & ~15;
    const int sub   = wl & 15;
    const int g2    = sub >> 3;        // edge half (0/1)
    const int l8    = sub & 7;         // dim slice

    const unsigned beg = offsets[node];
    const int cnt = (int)counts[node];
    if (cnt == 0) {
        if (sub < 8) {
            const float4 zz = make_float4(0.f, 0.f, 0.f, 0.f);
            *(float4*)&out[(size_t)node * 64 + sub * 8]     = zz;
            *(float4*)&out[(size_t)node * 64 + sub * 8 + 4] = zz;
        }
        return;
    }

    const float invd = invden[node];
    const unsigned short* __restrict__ zrow = zb + l8 * 8;
    float acc[8] = {0.f, 0.f, 0.f, 0.f, 0.f, 0.f, 0.f, 0.f};

    for (int base = 0; base < cnt; base += 16) {
        const int rem = cnt - base;
        uint2 ep = make_uint2(0u, 0u);          // p=0, sj=0 for inactive slots
        if (sub < rem) ep = edge_ps[beg + base + sub];
        const float p = __uint_as_float(ep.x);
        const int  sj = (int)ep.y;

        uint4 vv[8];
#pragma unroll
        for (int k = 0; k < 8; ++k) {
            const int sjj = __shfl(sj, gbase + g2 * 8 + k);
            vv[k] = *(const uint4*)&zrow[(size_t)sjj * 64];
        }
#pragma unroll
        for (int k = 0; k < 8; ++k) {
            const float pj = __shfl(p, gbase + g2 * 8 + k);
            const uint4 v = vv[k];
#define UNPK(u, d0) \
            acc[d0]     = fmaf(pj, __uint_as_float((u) << 16),          acc[d0]); \
            acc[d0 + 1] = fmaf(pj, __uint_as_float((u) & 0xFFFF0000u), acc[d0 + 1]);
            UNPK(v.x, 0) UNPK(v.y, 2) UNPK(v.z, 4) UNPK(v.w, 6)
#undef UNPK
        }
    }

#pragma unroll
    for (int c = 0; c < 8; ++c)
        acc[c] += __shfl_xor(acc[c], 8);

    if (sub < 8) {
        float4 o0 = make_float4(acc[0] * invd, acc[1] * invd, acc[2] * invd, acc[3] * invd);
        float4 o1 = make_float4(acc[4] * invd, acc[5] * invd, acc[6] * invd, acc[7] * invd);
        *(float4*)&out[(size_t)node * 64 + sub * 8]     = o0;
        *(float4*)&out[(size_t)node * 64 + sub * 8 + 4] = o1;
    }
}

extern "C" void kernel_launch(void* const* d_in, const int* in_sizes, int n_in,
                              void* d_out, int out_size, void* d_ws, size_t ws_size,
                              hipStream_t stream) {
    const float* h   = (const float*)d_in[0];
    const int*   src = (const int*)d_in[1];
    const int*   dst = (const int*)d_in[2];
    const float* W1  = (const float*)d_in[3];
    const float* Wa  = (const float*)d_in[4];
    float* out = (float*)d_out;

    const int N = in_sizes[0] / 128;
    const int E = in_sizes[1];
    const int NBKT = (N + NPB - 1) / NPB;            // <=256
    const int meanb = (E + NBKT - 1) / NBKT;
    int slack = 24 * (int)sqrtf((float)meanb) + 64;  // mean + 24 sigma
    const int BCAP = meanb + slack;

    const int G1 = (N + GROWS - 1) / GROWS;          // gemm blocks (64 rows each)
    const int G2 = (E + CHUNK - 1) / CHUNK;          // partition blocks

    // ws: zb(N*64 bf16) | s(N) | t(N) | gcur(NBKT) | offsets(N) | counts(N) |
    //     invden(N) | edge_ps(E u64) | table(NBKT*BCAP)
    unsigned short* zb = (unsigned short*)d_ws;
    float*    s        = (float*)(zb + (size_t)N * 64);
    float*    t        = s + N;
    unsigned* gcur     = (unsigned*)(t + N);
    unsigned* offsets  = gcur + NBKT;
    unsigned* counts   = offsets + N;
    float*    invden   = (float*)(counts + N);
    uint2*    edge_ps  = (uint2*)(invden + N);
    unsigned* table    = (unsigned*)(edge_ps + E);

    hipMemsetAsync(gcur, 0, (size_t)NBKT * sizeof(unsigned), stream);

    k_gp<<<G1 + G2, 256, 0, stream>>>(h, W1, Wa, zb, s, t, N, G1,
                                      src, dst, gcur, table, E, NBKT, BCAP);
    k_sp<<<NBKT, 512, 0, stream>>>(table, gcur, s, t, edge_ps, offsets, counts,
                                   invden, N, NBKT, BCAP);
    k_node<<<(N + 15) / 16, 256, 0, stream>>>(offsets, counts, edge_ps, invden, zb, out, N);
}

// Round 18
// 96.267 us; speedup vs baseline: 1.2423x; 1.2423x over previous
//
#include <hip/hip_runtime.h>
#include <hip/hip_bf16.h>

#define NEG_SLOPE 0.01f
#define NPB 512          // nodes per coarse bucket (dst >> 9)
#define CHUNK 4096       // edges per block in partition pass

typedef __attribute__((ext_vector_type(8))) short short8;
typedef __attribute__((ext_vector_type(4))) short short4v;
typedef __attribute__((ext_vector_type(4))) float f32x4;

__device__ __forceinline__ unsigned short f2bf_rne(float f) {
    __hip_bfloat16 b = __float2bfloat16(f);       // HW v_cvt, RNE
    return __builtin_bit_cast(unsigned short, b);
}

__device__ __forceinline__ short8 cvt2(float4 v0, float4 v1) {
    short8 o;
    o[0]=(short)f2bf_rne(v0.x); o[1]=(short)f2bf_rne(v0.y);
    o[2]=(short)f2bf_rne(v0.z); o[3]=(short)f2bf_rne(v0.w);
    o[4]=(short)f2bf_rne(v1.x); o[5]=(short)f2bf_rne(v1.y);
    o[6]=(short)f2bf_rne(v1.z); o[7]=(short)f2bf_rne(v1.w);
    return o;
}

// Fused K1: blocks [0, G1) = MFMA GEMM (SWAPPED operands -> z^T tiles: each
// lane owns ONE node's dims -> direct stores, no LDS transpose, 2-shfl s/t
// epilogue); blocks [G1, G1+G2) = edge partition pass.
__global__ __launch_bounds__(256, 4) void k_gp(
    const float* __restrict__ h, const float* __restrict__ W1,
    const float* __restrict__ Wa, unsigned short* __restrict__ zb,
    float* __restrict__ s, float* __restrict__ t, int N, int G1,
    const int* __restrict__ src, const int* __restrict__ dst,
    unsigned* __restrict__ gcur, unsigned* __restrict__ table,
    int E, int NBKT, int BCAP)
{
    __shared__ __align__(16) union SM {
        short wsb[64 * 128];                                             // 16 KB
        struct {
            unsigned cnt[256]; unsigned exc[256]; unsigned sbuf[256];
            unsigned gbaseb[256]; unsigned stage[CHUNK];
            unsigned short bkt[CHUNK];
        } p;                                                             // 28 KB
    } sm;
    const int tid = threadIdx.x;

    if (blockIdx.x < (unsigned)G1) {
        // ---------------- GEMM path ----------------
        const int nb = blockIdx.x * 256;
        const int w  = tid >> 6;
        const int l  = tid & 63;
        const int lr = l & 15;
        const int lc = l >> 4;
        const int wavebase = nb + w * 64;
        const float4* __restrict__ h4 = (const float4*)h;
        const float4* __restrict__ W14 = (const float4*)W1;

        // a_src/a_dst slices for this lane's dims {ni*16 + lc*4 .. +3}
        float4 as4[4], ad4[4];
#pragma unroll
        for (int ni = 0; ni < 4; ++ni) {
            as4[ni] = *(const float4*)&Wa[ni * 16 + lc * 4];
            ad4[ni] = *(const float4*)&Wa[64 + ni * 16 + lc * 4];
        }

        // Prologue: rg 0's h loads (8 x 16B, independent).
        float4 av[8];
        {
            const int myn = wavebase + lr;
#pragma unroll
            for (int ks = 0; ks < 4; ++ks) {
                const int kcb = ks * 4 + lc;
                if (myn < N) {
                    av[2 * ks]     = h4[(size_t)myn * 32 + kcb * 2];
                    av[2 * ks + 1] = h4[(size_t)myn * 32 + kcb * 2 + 1];
                } else {
                    av[2 * ks]     = make_float4(0.f, 0.f, 0.f, 0.f);
                    av[2 * ks + 1] = make_float4(0.f, 0.f, 0.f, 0.f);
                }
            }
        }

        // Stage W1 (64x128) into LDS bf16, XOR-swizzled for b128 reads.
#pragma unroll
        for (int it = 0; it < 4; ++it) {
            const int q = tid + it * 256;
            const int r = q >> 4, cb = q & 15;
            float4 v0 = W14[(size_t)r * 32 + cb * 2];
            float4 v1 = W14[(size_t)r * 32 + cb * 2 + 1];
            *(short8*)&sm.wsb[r * 128 + ((cb * 8) ^ ((r & 7) << 3))] = cvt2(v0, v1);
        }
        __syncthreads();

#pragma unroll
        for (int rg = 0; rg < 4; ++rg) {
            // Convert current h loads to bf16 fragments.
            short8 afr[4];
#pragma unroll
            for (int ks = 0; ks < 4; ++ks) afr[ks] = cvt2(av[2 * ks], av[2 * ks + 1]);

            const int node = wavebase + rg * 16 + lr;    // this lane's node

            // Prefetch next rg's h loads (overlap with MFMA below).
            if (rg < 3) {
                const int myn = wavebase + (rg + 1) * 16 + lr;
#pragma unroll
                for (int ks = 0; ks < 4; ++ks) {
                    const int kcb = ks * 4 + lc;
                    if (myn < N) {
                        av[2 * ks]     = h4[(size_t)myn * 32 + kcb * 2];
                        av[2 * ks + 1] = h4[(size_t)myn * 32 + kcb * 2 + 1];
                    } else {
                        av[2 * ks]     = make_float4(0.f, 0.f, 0.f, 0.f);
                        av[2 * ks + 1] = make_float4(0.f, 0.f, 0.f, 0.f);
                    }
                }
            }

            // MFMA with SWAPPED operands: D = W-frag x h-frag -> z^T tile.
            // D: col(lane&15)=node, row((lane>>4)*4+reg)=dim within ni*16.
            f32x4 acc[4];
#pragma unroll
            for (int ni = 0; ni < 4; ++ni) acc[ni] = (f32x4){0.f, 0.f, 0.f, 0.f};
#pragma unroll
            for (int ks = 0; ks < 4; ++ks) {
                const int kcb = ks * 4 + lc;
#pragma unroll
                for (int ni = 0; ni < 4; ++ni) {
                    const int wr = ni * 16 + lr;
                    const short8 bfw = *(const short8*)&sm.wsb[wr * 128 + ((kcb * 8) ^ ((wr & 7) << 3))];
                    acc[ni] = __builtin_amdgcn_mfma_f32_16x16x32_bf16(bfw, afr[ks], acc[ni], 0, 0, 0);
                }
            }

            // s,t epilogue: lane holds 16 dims of its node; reduce across the
            // 4 lanes (lc=0..3) sharing this node via 2 shfls.
            {
                float ps = 0.f, pt = 0.f;
#pragma unroll
                for (int ni = 0; ni < 4; ++ni) {
                    ps = fmaf(acc[ni][0], as4[ni].x, ps); pt = fmaf(acc[ni][0], ad4[ni].x, pt);
                    ps = fmaf(acc[ni][1], as4[ni].y, ps); pt = fmaf(acc[ni][1], ad4[ni].y, pt);
                    ps = fmaf(acc[ni][2], as4[ni].z, ps); pt = fmaf(acc[ni][2], ad4[ni].z, pt);
                    ps = fmaf(acc[ni][3], as4[ni].w, ps); pt = fmaf(acc[ni][3], ad4[ni].w, pt);
                }
                ps += __shfl_xor(ps, 16); ps += __shfl_xor(ps, 32);
                pt += __shfl_xor(pt, 16); pt += __shfl_xor(pt, 32);
                if (l < 16 && node < N) { s[node] = ps; t[node] = pt; }
            }

            // Direct z stores: 4 x 8B per lane (dims ni*16+lc*4..+3 of node).
            if (node < N) {
#pragma unroll
                for (int ni = 0; ni < 4; ++ni) {
                    short4v o;
                    o[0] = (short)f2bf_rne(acc[ni][0]);
                    o[1] = (short)f2bf_rne(acc[ni][1]);
                    o[2] = (short)f2bf_rne(acc[ni][2]);
                    o[3] = (short)f2bf_rne(acc[ni][3]);
                    *(short4v*)&zb[(size_t)node * 64 + ni * 16 + lc * 4] = o;
                }
            }
        }
    } else {
        // ---------------- Partition path ----------------
        const int e0 = (blockIdx.x - G1) * CHUNK;
        const int nE = min(CHUNK, E - e0);

        sm.p.cnt[tid] = 0u;
        __syncthreads();
        for (int i = tid; i < nE; i += 256)
            atomicAdd(&sm.p.cnt[(unsigned)dst[e0 + i] >> 9], 1u);
        __syncthreads();

        const unsigned myc = sm.p.cnt[tid];
        if (tid < NBKT && myc > 0u) sm.p.gbaseb[tid] = atomicAdd(&gcur[tid], myc);

        sm.p.sbuf[tid] = myc;
        __syncthreads();
        for (int off = 1; off < 256; off <<= 1) {
            unsigned x = (tid >= off) ? sm.p.sbuf[tid - off] : 0u;
            __syncthreads();
            sm.p.sbuf[tid] += x;
            __syncthreads();
        }
        sm.p.exc[tid] = sm.p.sbuf[tid] - myc;
        __syncthreads();
        sm.p.cnt[tid] = 0u;
        __syncthreads();

        for (int i = tid; i < nE; i += 256) {
            const unsigned d = (unsigned)dst[e0 + i];
            const unsigned b = d >> 9;
            const unsigned pos = sm.p.exc[b] + atomicAdd(&sm.p.cnt[b], 1u);
            sm.p.stage[pos] = ((unsigned)src[e0 + i] << 9) | (d & 511u);
            sm.p.bkt[pos] = (unsigned short)b;
        }
        __syncthreads();

        for (int i = tid; i < nE; i += 256) {
            const unsigned b = sm.p.bkt[i];
            const unsigned off = sm.p.gbaseb[b] + ((unsigned)i - sm.p.exc[b]);
            if (off < (unsigned)BCAP)
                table[(size_t)b * BCAP + off] = sm.p.stage[i];
        }
    }
}

// Pass B (one block of 512 per coarse bucket): recompute global prefix,
// LDS histogram+scan over 512 nodes, then scatter WITH per-edge softmax
// numerator p = exp(leaky(s[src]+t[dst])) and LDS-atomic denominator.
__global__ __launch_bounds__(512) void k_sp(
    const unsigned* __restrict__ table, const unsigned* __restrict__ gcur,
    const float* __restrict__ s, const float* __restrict__ t,
    uint2* __restrict__ edge_ps, unsigned* __restrict__ offsets,
    unsigned* __restrict__ counts, float* __restrict__ invden,
    int N, int NBKT, int BCAP)
{
    __shared__ unsigned ncnt[NPB], nexc[NPB], scur[NPB], sbuf[NPB];
    __shared__ float tlds[NPB], den[NPB];
    __shared__ unsigned basesh;
    const int tid = threadIdx.x;
    const int b = blockIdx.x;
    const int bc = min((int)gcur[b], BCAP);
    const size_t tbo = (size_t)b * BCAP;
    const int node = b * NPB + tid;

    {
        unsigned c = (tid < NBKT) ? min(gcur[tid], (unsigned)BCAP) : 0u;
        sbuf[tid] = c;
        __syncthreads();
        for (int off = 1; off < NPB; off <<= 1) {
            unsigned x = (tid >= off) ? sbuf[tid - off] : 0u;
            __syncthreads();
            sbuf[tid] += x;
            __syncthreads();
        }
        if (tid == 0) basesh = (b == 0) ? 0u : sbuf[b - 1];
    }
    tlds[tid] = (node < N) ? t[node] : 0.f;
    den[tid] = 0.f;
    ncnt[tid] = 0u;
    __syncthreads();
    const unsigned base = basesh;

    for (int i = tid; i < bc; i += NPB)
        atomicAdd(&ncnt[table[tbo + i] & 511u], 1u);
    __syncthreads();

    const unsigned c0 = ncnt[tid];
    sbuf[tid] = c0;
    __syncthreads();
    for (int off = 1; off < NPB; off <<= 1) {
        unsigned x = (tid >= off) ? sbuf[tid - off] : 0u;
        __syncthreads();
        sbuf[tid] += x;
        __syncthreads();
    }
    nexc[tid] = sbuf[tid] - c0;
    scur[tid] = 0u;
    __syncthreads();

    if (node < N) { offsets[node] = base + nexc[tid]; counts[node] = c0; }

    for (int i = tid; i < bc; i += NPB) {
        const unsigned v = table[tbo + i];
        const unsigned l = v & 511u;
        const unsigned sj = v >> 9;
        float e = s[sj] + tlds[l];
        e = (e >= 0.f) ? e : NEG_SLOPE * e;
        const float p = __expf(e);
        const unsigned pos = nexc[l] + atomicAdd(&scur[l], 1u);
        edge_ps[base + pos] = make_uint2(__float_as_uint(p), sj);
        atomicAdd(&den[l], p);
    }
    __syncthreads();
    if (node < N) invden[node] = 1.f / fmaxf(den[tid], 1e-16f);
}

// Pure gather-accumulate: out[node] = invden * sum p_j * z[src_j].
__global__ __launch_bounds__(256) void k_node(
    const unsigned* __restrict__ offsets, const unsigned* __restrict__ counts,
    const uint2* __restrict__ edge_ps, const float* __restrict__ invden,
    const unsigned short* __restrict__ zb, float* __restrict__ out, int N)
{
    const int tid = threadIdx.x;
    const int node = blockIdx.x * 16 + (tid >> 4);
    if (node >= N) return;
    const int wl    = tid & 63;
    const int gbase = wl & ~15;
    const int sub   = wl & 15;
    const int g2    = sub >> 3;        // edge half (0/1)
    const int l8    = sub & 7;         // dim slice

    const unsigned beg = offsets[node];
    const int cnt = (int)counts[node];
    if (cnt == 0) {
        if (sub < 8) {
            const float4 zz = make_float4(0.f, 0.f, 0.f, 0.f);
            *(float4*)&out[(size_t)node * 64 + sub * 8]     = zz;
            *(float4*)&out[(size_t)node * 64 + sub * 8 + 4] = zz;
        }
        return;
    }

    const float invd = invden[node];
    const unsigned short* __restrict__ zrow = zb + l8 * 8;
    float acc[8] = {0.f, 0.f, 0.f, 0.f, 0.f, 0.f, 0.f, 0.f};

    for (int base = 0; base < cnt; base += 16) {
        const int rem = cnt - base;
        uint2 ep = make_uint2(0u, 0u);          // p=0, sj=0 for inactive slots
        if (sub < rem) ep = edge_ps[beg + base + sub];
        const float p = __uint_as_float(ep.x);
        const int  sj = (int)ep.y;

        uint4 vv[8];
#pragma unroll
        for (int k = 0; k < 8; ++k) {
            const int sjj = __shfl(sj, gbase + g2 * 8 + k);
            vv[k] = *(const uint4*)&zrow[(size_t)sjj * 64];
        }
#pragma unroll
        for (int k = 0; k < 8; ++k) {
            const float pj = __shfl(p, gbase + g2 * 8 + k);
            const uint4 v = vv[k];
#define UNPK(u, d0) \
            acc[d0]     = fmaf(pj, __uint_as_float((u) << 16),          acc[d0]); \
            acc[d0 + 1] = fmaf(pj, __uint_as_float((u) & 0xFFFF0000u), acc[d0 + 1]);
            UNPK(v.x, 0) UNPK(v.y, 2) UNPK(v.z, 4) UNPK(v.w, 6)
#undef UNPK
        }
    }

#pragma unroll
    for (int c = 0; c < 8; ++c)
        acc[c] += __shfl_xor(acc[c], 8);

    if (sub < 8) {
        float4 o0 = make_float4(acc[0] * invd, acc[1] * invd, acc[2] * invd, acc[3] * invd);
        float4 o1 = make_float4(acc[4] * invd, acc[5] * invd, acc[6] * invd, acc[7] * invd);
        *(float4*)&out[(size_t)node * 64 + sub * 8]     = o0;
        *(float4*)&out[(size_t)node * 64 + sub * 8 + 4] = o1;
    }
}

extern "C" void kernel_launch(void* const* d_in, const int* in_sizes, int n_in,
                              void* d_out, int out_size, void* d_ws, size_t ws_size,
                              hipStream_t stream) {
    const float* h   = (const float*)d_in[0];
    const int*   src = (const int*)d_in[1];
    const int*   dst = (const int*)d_in[2];
    const float* W1  = (const float*)d_in[3];
    const float* Wa  = (const float*)d_in[4];
    float* out = (float*)d_out;

    const int N = in_sizes[0] / 128;
    const int E = in_sizes[1];
    const int NBKT = (N + NPB - 1) / NPB;            // <=256
    const int meanb = (E + NBKT - 1) / NBKT;
    int slack = 24 * (int)sqrtf((float)meanb) + 64;  // mean + 24 sigma
    const int BCAP = meanb + slack;

    const int G1 = (N + 255) / 256;                  // gemm blocks (256 rows each)
    const int G2 = (E + CHUNK - 1) / CHUNK;          // partition blocks

    // ws: zb(N*64 bf16) | s(N) | t(N) | gcur(NBKT) | offsets(N) | counts(N) |
    //     invden(N) | edge_ps(E u64) | table(NBKT*BCAP)
    unsigned short* zb = (unsigned short*)d_ws;
    float*    s        = (float*)(zb + (size_t)N * 64);
    float*    t        = s + N;
    unsigned* gcur     = (unsigned*)(t + N);
    unsigned* offsets  = gcur + NBKT;
    unsigned* counts   = offsets + N;
    float*    invden   = (float*)(counts + N);
    uint2*    edge_ps  = (uint2*)(invden + N);
    unsigned* table    = (unsigned*)(edge_ps + E);

    hipMemsetAsync(gcur, 0, (size_t)NBKT * sizeof(unsigned), stream);

    k_gp<<<G1 + G2, 256, 0, stream>>>(h, W1, Wa, zb, s, t, N, G1,
                                      src, dst, gcur, table, E, NBKT, BCAP);
    k_sp<<<NBKT, 512, 0, stream>>>(table, gcur, s, t, edge_ps, offsets, counts,
                                   invden, N, NBKT, BCAP);
    k_node<<<(N + 15) / 16, 256, 0, stream>>>(offsets, counts, edge_ps, invden, zb, out, N);
}